// Round 8
// baseline (159.466 us; speedup 1.0000x reference)
//
#include <hip/hip_runtime.h>
#include <math.h>

#define LAM 0.9f
#define EPS 1e-8f
#define RPB 256   // rows per block

typedef float f32x4 __attribute__((ext_vector_type(4)));
typedef float f32x2 __attribute__((ext_vector_type(2)));

// Pin an SSA value into a VGPR tuple at this program point (forces the load
// to have completed-materialized here; no memory clobber, deterministic).
#define PIN(x) asm volatile("" : "+v"(x))

// log-weight: 0.9*log(fir+eps) + 0.1*log(fir-sec+eps) over 10 probs
__device__ __forceinline__ float row_logw(const float* __restrict__ p) {
    float fir = -3.4e38f, sec = -3.4e38f;
    const f32x2* p2 = (const f32x2*)p;   // rows are 40B -> 8B-aligned
#pragma unroll
    for (int i = 0; i < 5; ++i) {
        f32x2 x = p2[i];
        if (x.x > fir) { sec = fir; fir = x.x; }
        else if (x.x > sec) { sec = x.x; }
        if (x.y > fir) { sec = fir; fir = x.y; }
        else if (x.y > sec) { sec = x.y; }
    }
    return LAM * __logf(fir + EPS) + (1.0f - LAM) * __logf(fir - sec + EPS);
}

__global__ __launch_bounds__(256) void fused_blend_kernel(
    const float* __restrict__ v1, const float* __restrict__ p1,
    const float* __restrict__ v2, const float* __restrict__ p2,
    float* __restrict__ out, int N)
{
    __shared__ float b1s[RPB];
    const int t   = threadIdx.x;
    const int t32 = t >> 5;
    const int rowBase = blockIdx.x * RPB;
    const int row = rowBase + t;
    const unsigned gBase = (unsigned)rowBase * 32u + (unsigned)t;   // flat float4 index

    const f32x4* __restrict__ v1q = (const f32x4*)v1;
    const f32x4* __restrict__ v2q = (const f32x4*)v2;
    f32x4* __restrict__ outq = (f32x4*)out;

    const bool full = (rowBase + RPB <= N);   // uniform per block

    if (full) {
        f32x4 a[8], b[8];

        // Chunk 0 loads primed BEFORE the beta phase (latency hides under
        // the prob loads + transcendentals).
#pragma unroll
        for (int j = 0; j < 8; ++j) {
            a[j] = v1q[gBase + (unsigned)j * 256u];
            b[j] = v2q[gBase + (unsigned)j * 256u];
        }
#pragma unroll
        for (int j = 0; j < 8; ++j) { PIN(a[j]); PIN(b[j]); }

        // Phase 1: every thread computes beta1 for its own row.
        const float a1 = row_logw(p1 + (size_t)row * 10);
        const float a2 = row_logw(p2 + (size_t)row * 10);
        b1s[t] = 1.0f / (1.0f + __expf(a2 - a1));   // w1/(w1+w2) = sigmoid(a1-a2)
        __syncthreads();

        // Phase 2: 4 chunks of 8 pairs. The PIN wall between the load batch
        // and the store batch forces all 16 loads of a chunk to be issued
        // (and live) before any blend consumes one -> 16-deep MLP per wave.
#pragma unroll
        for (int c = 0; c < 4; ++c) {
            if (c > 0) {
#pragma unroll
                for (int j = 0; j < 8; ++j) {
                    a[j] = v1q[gBase + (unsigned)(c * 8 + j) * 256u];
                    b[j] = v2q[gBase + (unsigned)(c * 8 + j) * 256u];
                }
#pragma unroll
                for (int j = 0; j < 8; ++j) { PIN(a[j]); PIN(b[j]); }
            }
#pragma unroll
            for (int j = 0; j < 8; ++j) {
                const float be1 = b1s[(c * 8 + j) * 8 + t32];
                const f32x4 r = be1 * a[j] + (1.0f - be1) * b[j];
                __builtin_nontemporal_store(r, outq + gBase + (unsigned)(c * 8 + j) * 256u);
            }
        }
    } else {
        // Tail block (at most one): fully bounds-checked path.
        if (row < N) {
            const float a1 = row_logw(p1 + (size_t)row * 10);
            const float a2 = row_logw(p2 + (size_t)row * 10);
            b1s[t] = 1.0f / (1.0f + __expf(a2 - a1));
        }
        __syncthreads();
        const unsigned gEnd = (unsigned)N * 32u;
        for (int k = 0; k < 32; ++k) {
            const unsigned g = (unsigned)rowBase * 32u + (unsigned)k * 256u + (unsigned)t;
            if (g < gEnd) {
                const float be1 = b1s[(k * 256 + t) >> 5];
                const f32x4 va = v1q[g];
                const f32x4 vb = v2q[g];
                __builtin_nontemporal_store(be1 * va + (1.0f - be1) * vb, outq + g);
            }
        }
    }
}

extern "C" void kernel_launch(void* const* d_in, const int* in_sizes, int n_in,
                              void* d_out, int out_size, void* d_ws, size_t ws_size,
                              hipStream_t stream) {
    const float* v1 = (const float*)d_in[0];
    const float* p1 = (const float*)d_in[1];
    const float* v2 = (const float*)d_in[2];
    const float* p2 = (const float*)d_in[3];
    float* out = (float*)d_out;
    const int N = in_sizes[1] / 10;  // prob_v1 is (N, 10)

    const int blocks = (N + RPB - 1) / RPB;
    fused_blend_kernel<<<blocks, 256, 0, stream>>>(v1, p1, v2, p2, out, N);
}

// Round 9
// 152.088 us; speedup vs baseline: 1.0485x; 1.0485x over previous
//
#include <hip/hip_runtime.h>
#include <math.h>

#define LAM 0.9f
#define EPS 1e-8f
#define RPB 256   // rows per block

typedef float f32x4 __attribute__((ext_vector_type(4)));
typedef float f32x2 __attribute__((ext_vector_type(2)));

// log-weight: 0.9*log(fir+eps) + 0.1*log(fir-sec+eps) over 10 probs
__device__ __forceinline__ float row_logw(const float* __restrict__ p) {
    float fir = -3.4e38f, sec = -3.4e38f;
    const f32x2* p2 = (const f32x2*)p;   // rows are 40B -> 8B-aligned
#pragma unroll
    for (int i = 0; i < 5; ++i) {
        f32x2 x = p2[i];
        if (x.x > fir) { sec = fir; fir = x.x; }
        else if (x.x > sec) { sec = x.x; }
        if (x.y > fir) { sec = fir; fir = x.y; }
        else if (x.y > sec) { sec = x.y; }
    }
    return LAM * __logf(fir + EPS) + (1.0f - LAM) * __logf(fir - sec + EPS);
}

__global__ __launch_bounds__(256) void fused_blend_kernel(
    const float* __restrict__ v1, const float* __restrict__ p1,
    const float* __restrict__ v2, const float* __restrict__ p2,
    float* __restrict__ out, int N)
{
    __shared__ float b1s[RPB];
    const int t   = threadIdx.x;
    const int t32 = t >> 5;
    const int rowBase = blockIdx.x * RPB;
    const int row = rowBase + t;
    const unsigned gBase = (unsigned)rowBase * 32u + (unsigned)t;   // flat float4 index

    const f32x4* __restrict__ v1q = (const f32x4*)v1;
    const f32x4* __restrict__ v2q = (const f32x4*)v2;
    f32x4* __restrict__ outq = (f32x4*)out;

    const bool full = (rowBase + RPB <= N);   // uniform per block

    if (full) {
        // Rotating window, distance 8 (best measured variant: 152.0 us).
        f32x4 a[8], b[8];

        // Prime the window: issue pairs 0..7 before the beta phase so their
        // HBM latency hides under the prob loads + transcendentals.
#pragma unroll
        for (int j = 0; j < 8; ++j) {
            a[j] = v1q[gBase + (unsigned)j * 256u];
            b[j] = v2q[gBase + (unsigned)j * 256u];
        }

        // Phase 1: every thread computes beta1 for its own row.
        const float a1 = row_logw(p1 + (size_t)row * 10);
        const float a2 = row_logw(p2 + (size_t)row * 10);
        b1s[t] = 1.0f / (1.0f + __expf(a2 - a1));   // w1/(w1+w2) = sigmoid(a1-a2)
        __syncthreads();

        // Phase 2: blend+store pair k, then refill its slot with pair k+8.
#pragma unroll
        for (int k = 0; k < 32; ++k) {
            const int s = k & 7;
            const float be1 = b1s[k * 8 + t32];
            const f32x4 r = be1 * a[s] + (1.0f - be1) * b[s];
            __builtin_nontemporal_store(r, outq + gBase + (unsigned)k * 256u);
            if (k < 24) {
                a[s] = v1q[gBase + (unsigned)(k + 8) * 256u];
                b[s] = v2q[gBase + (unsigned)(k + 8) * 256u];
            }
        }
    } else {
        // Tail block (at most one): fully bounds-checked path.
        if (row < N) {
            const float a1 = row_logw(p1 + (size_t)row * 10);
            const float a2 = row_logw(p2 + (size_t)row * 10);
            b1s[t] = 1.0f / (1.0f + __expf(a2 - a1));
        }
        __syncthreads();
        const unsigned gEnd = (unsigned)N * 32u;
        for (int k = 0; k < 32; ++k) {
            const unsigned g = (unsigned)rowBase * 32u + (unsigned)k * 256u + (unsigned)t;
            if (g < gEnd) {
                const float be1 = b1s[(k * 256 + t) >> 5];
                const f32x4 va = v1q[g];
                const f32x4 vb = v2q[g];
                __builtin_nontemporal_store(be1 * va + (1.0f - be1) * vb, outq + g);
            }
        }
    }
}

extern "C" void kernel_launch(void* const* d_in, const int* in_sizes, int n_in,
                              void* d_out, int out_size, void* d_ws, size_t ws_size,
                              hipStream_t stream) {
    const float* v1 = (const float*)d_in[0];
    const float* p1 = (const float*)d_in[1];
    const float* v2 = (const float*)d_in[2];
    const float* p2 = (const float*)d_in[3];
    float* out = (float*)d_out;
    const int N = in_sizes[1] / 10;  // prob_v1 is (N, 10)

    const int blocks = (N + RPB - 1) / RPB;
    fused_blend_kernel<<<blocks, 256, 0, stream>>>(v1, p1, v2, p2, out, N);
}